// Round 1
// baseline (212.746 us; speedup 1.0000x reference)
//
#include <hip/hip_runtime.h>

#define NEG_INF -9.0e15f

using short8 = __attribute__((ext_vector_type(8))) short;
using f32x4  = __attribute__((ext_vector_type(4))) float;

__device__ __forceinline__ unsigned short f2bf(float f) {
  unsigned u = __float_as_uint(f);
  u += 0x7fffu + ((u >> 16) & 1u);
  return (unsigned short)(u >> 16);
}
__device__ __forceinline__ float bf2f(unsigned short h) {
  return __uint_as_float(((unsigned)h) << 16);
}

// ---------------- Kernel A: temporal conv over flattened (N*F_IN) axis ----------------
// x: [B=4][N=2048][T=12][F=32] f32 ; out xt: [b][n][t*32+f] bf16
__global__ __launch_bounds__(256) void conv_kernel(const float* __restrict__ x,
                                                   const float* __restrict__ cw,
                                                   const float* __restrict__ cb,
                                                   unsigned short* __restrict__ xt) {
  __shared__ float tile[12][264];   // 258 used
  __shared__ float cws[432];
  __shared__ float cbs[12];
  const int b  = blockIdx.y;
  const int p0 = blockIdx.x << 8;
  const int tid = threadIdx.x;
  for (int i = tid; i < 432; i += 256) cws[i] = cw[i];
  if (tid < 12) cbs[tid] = cb[tid];
  for (int t = 0; t < 12; ++t) {
    for (int i = tid; i < 258; i += 256) {
      int gp = p0 + i - 1;
      float v = 0.f;
      if (gp >= 0 && gp < 2048 * 32) {
        int n = gp >> 5, f = gp & 31;
        v = x[(((size_t)b * 2048 + n) * 12 + t) * 32 + f];
      }
      tile[t][i] = v;
    }
  }
  __syncthreads();
  float acc[12];
#pragma unroll
  for (int to = 0; to < 12; ++to) acc[to] = cbs[to];
#pragma unroll
  for (int ti = 0; ti < 12; ++ti) {
    float x0 = tile[ti][tid], x1 = tile[ti][tid + 1], x2 = tile[ti][tid + 2];
#pragma unroll
    for (int to = 0; to < 12; ++to) {
      const float* wp = &cws[(to * 12 + ti) * 3];
      acc[to] += x0 * wp[0] + x1 * wp[1] + x2 * wp[2];
    }
  }
  const int p = p0 + tid, n = p >> 5, f = p & 31;
  unsigned short* op = xt + ((size_t)b * 2048 + n) * 384 + f;
#pragma unroll
  for (int to = 0; to < 12; ++to) op[to * 32] = f2bf(acc[to]);
}

// ---------------- Transpose f32 [z][rows][cols] -> bf16 [z][cols][rows] ----------------
__global__ __launch_bounds__(256) void transpose_bf16_kernel(const float* __restrict__ in,
                                                             unsigned short* __restrict__ out,
                                                             int rows, int cols) {
  __shared__ float tile[32][33];
  const size_t base = (size_t)blockIdx.z * rows * cols;
  const int r0 = blockIdx.x * 32, c0 = blockIdx.y * 32;
  const int li = threadIdx.x >> 5, ci = threadIdx.x & 31;
#pragma unroll
  for (int p = 0; p < 4; ++p) {
    int r = li + p * 8;
    tile[r][ci] = in[base + (size_t)(r0 + r) * cols + c0 + ci];
  }
  __syncthreads();
#pragma unroll
  for (int p = 0; p < 4; ++p) {
    int c = li + p * 8;
    out[base + (size_t)(c0 + c) * rows + r0 + ci] = f2bf(tile[ci][c]);
  }
}

// ---------------- Kernel B: Wh = xt @ W  (8192x384 @ 384x384, bf16 MFMA) ----------------
// xt: [8192][384] bf16 row-major; Wt: [384(col)][384(k)] bf16 ; Wh: f32 [8192][384]
__global__ __launch_bounds__(384) void gemm_wh_kernel(const unsigned short* __restrict__ xt,
                                                      const unsigned short* __restrict__ Wt,
                                                      float* __restrict__ Wh) {
  const int r0 = blockIdx.x << 4;
  const int w = threadIdx.x >> 6;
  const int lane = threadIdx.x & 63;
  const int il = lane & 15, kg = lane >> 4;
  f32x4 acc[4];
#pragma unroll
  for (int t = 0; t < 4; ++t) acc[t] = (f32x4){0.f, 0.f, 0.f, 0.f};
  const unsigned short* ap = xt + (size_t)(r0 + il) * 384 + kg * 8;
#pragma unroll
  for (int kk = 0; kk < 12; ++kk) {
    short8 af = *reinterpret_cast<const short8*>(ap + kk * 32);
#pragma unroll
    for (int t = 0; t < 4; ++t) {
      int c = (w << 6) + (t << 4) + il;
      short8 bf = *reinterpret_cast<const short8*>(Wt + (size_t)c * 384 + kk * 32 + kg * 8);
      acc[t] = __builtin_amdgcn_mfma_f32_16x16x32_bf16(af, bf, acc[t], 0, 0, 0);
    }
  }
#pragma unroll
  for (int t = 0; t < 4; ++t)
#pragma unroll
    for (int r = 0; r < 4; ++r)
      Wh[(size_t)(r0 + kg * 4 + r) * 384 + (w << 6) + (t << 4) + il] = acc[t][r];
}

// ---------------- Kernel C: f1 = Wh@a1, f2 = Wh@a2 (wave per row) ----------------
__global__ __launch_bounds__(256) void f1f2_kernel(const float* __restrict__ Wh,
                                                   const float* __restrict__ a,
                                                   float* __restrict__ f1,
                                                   float* __restrict__ f2) {
  const int wid = (int)((blockIdx.x * 256 + threadIdx.x) >> 6);  // 0..8191
  const int lane = threadIdx.x & 63;
  const float* row = Wh + (size_t)wid * 384;
  float s1 = 0.f, s2 = 0.f;
#pragma unroll
  for (int k = 0; k < 6; ++k) {
    int c = lane + (k << 6);
    float v = row[c];
    s1 += v * a[c];
    s2 += v * a[384 + c];
  }
#pragma unroll
  for (int off = 32; off; off >>= 1) {
    s1 += __shfl_xor(s1, off);
    s2 += __shfl_xor(s2, off);
  }
  if (lane == 0) { f1[wid] = s1; f2[wid] = s2; }
}

// ---------------- Kernel E: masked softmax attention + PV + elu ----------------
// block = (b, 16 i-rows); 4 waves, wave w owns cols [w*96, w*96+96)
// WhT: [b][c=384][n=2048] bf16
__global__ __launch_bounds__(256) void attn_kernel(const float* __restrict__ f1,
                                                   const float* __restrict__ f2,
                                                   const int* __restrict__ adj,
                                                   const unsigned short* __restrict__ WhT,
                                                   float* __restrict__ out) {
  const int blk = blockIdx.x;
  const int b = blk >> 7;
  const int i0 = (blk & 127) << 4;
  const int tid = threadIdx.x;
  const int w = tid >> 6;
  const int lane = tid & 63;
  const int il = lane & 15, kg = lane >> 4;
  const int ig = i0 + il;
  const int* adjrow = adj + (size_t)ig * 2048;
  const float f1v = f1[b * 2048 + ig];
  const float* f2b = f2 + b * 2048;
  const unsigned short* whtb = WhT + (size_t)b * 384 * 2048;

  // ---- pass 1: row max of masked leaky_relu logits ----
  float m = NEG_INF;
  for (int jb = kg * 8; jb < 2048; jb += 32) {
    int4 a0 = *reinterpret_cast<const int4*>(adjrow + jb);
    int4 a1 = *reinterpret_cast<const int4*>(adjrow + jb + 4);
    float4 g0 = *reinterpret_cast<const float4*>(f2b + jb);
    float4 g1 = *reinterpret_cast<const float4*>(f2b + jb + 4);
    int av[8] = {a0.x, a0.y, a0.z, a0.w, a1.x, a1.y, a1.z, a1.w};
    float gv[8] = {g0.x, g0.y, g0.z, g0.w, g1.x, g1.y, g1.z, g1.w};
#pragma unroll
    for (int u = 0; u < 8; ++u) {
      float z = f1v + gv[u];
      float e = z > 0.f ? z : 0.2f * z;
      e = av[u] > 0 ? e : NEG_INF;
      m = fmaxf(m, e);
    }
  }
  m = fmaxf(m, __shfl_xor(m, 16));
  m = fmaxf(m, __shfl_xor(m, 32));

  // ---- pass 2: accumulate exp(e-m) * Wh via MFMA ----
  f32x4 acc[6];
#pragma unroll
  for (int t = 0; t < 6; ++t) acc[t] = (f32x4){0.f, 0.f, 0.f, 0.f};
  float denom = 0.f;

  for (int jb = kg * 8; jb < 2048; jb += 32) {
    int4 a0 = *reinterpret_cast<const int4*>(adjrow + jb);
    int4 a1 = *reinterpret_cast<const int4*>(adjrow + jb + 4);
    float4 g0 = *reinterpret_cast<const float4*>(f2b + jb);
    float4 g1 = *reinterpret_cast<const float4*>(f2b + jb + 4);
    int av[8] = {a0.x, a0.y, a0.z, a0.w, a1.x, a1.y, a1.z, a1.w};
    float gv[8] = {g0.x, g0.y, g0.z, g0.w, g1.x, g1.y, g1.z, g1.w};
    short8 af;
    float ssum = 0.f;
#pragma unroll
    for (int u = 0; u < 8; ++u) {
      float z = f1v + gv[u];
      float e = z > 0.f ? z : 0.2f * z;
      e = av[u] > 0 ? e : NEG_INF;
      float s = __expf(e - m);
      unsigned short h = f2bf(s);
      af[u] = (short)h;
      ssum += bf2f(h);
    }
    denom += ssum;
#pragma unroll
    for (int t = 0; t < 6; ++t) {
      int c = w * 96 + t * 16 + il;
      short8 bf = *reinterpret_cast<const short8*>(whtb + (size_t)c * 2048 + jb);
      acc[t] = __builtin_amdgcn_mfma_f32_16x16x32_bf16(af, bf, acc[t], 0, 0, 0);
    }
  }
  denom += __shfl_xor(denom, 16);
  denom += __shfl_xor(denom, 32);

#pragma unroll
  for (int t = 0; t < 6; ++t) {
#pragma unroll
    for (int r = 0; r < 4; ++r) {
      int ir = kg * 4 + r;
      float dd = __shfl(denom, ir);
      float v = acc[t][r] / dd;
      v = v > 0.f ? v : expm1f(v);
      out[((size_t)b * 2048 + i0 + ir) * 384 + w * 96 + t * 16 + il] = v;
    }
  }
}

extern "C" void kernel_launch(void* const* d_in, const int* in_sizes, int n_in,
                              void* d_out, int out_size, void* d_ws, size_t ws_size,
                              hipStream_t stream) {
  const float* x  = (const float*)d_in[0];
  const int* adj  = (const int*)d_in[1];
  const float* W  = (const float*)d_in[2];
  const float* a  = (const float*)d_in[3];
  const float* cw = (const float*)d_in[4];
  const float* cb = (const float*)d_in[5];
  float* out = (float*)d_out;

  char* ws = (char*)d_ws;
  unsigned short* xt  = (unsigned short*)ws; ws += (size_t)3145728 * 2;  // [8192][384] bf16
  unsigned short* Wt  = (unsigned short*)ws; ws += (size_t)147456 * 2;   // [384][384] bf16 (transposed)
  float* Wh           = (float*)ws;          ws += (size_t)3145728 * 4;  // [8192][384] f32
  unsigned short* WhT = (unsigned short*)ws; ws += (size_t)3145728 * 2;  // [4][384][2048] bf16
  float* f1           = (float*)ws;          ws += (size_t)8192 * 4;
  float* f2           = (float*)ws;          ws += (size_t)8192 * 4;

  conv_kernel<<<dim3(256, 4), 256, 0, stream>>>(x, cw, cb, xt);
  transpose_bf16_kernel<<<dim3(12, 12, 1), 256, 0, stream>>>(W, Wt, 384, 384);
  gemm_wh_kernel<<<dim3(512), 384, 0, stream>>>(xt, Wt, Wh);
  f1f2_kernel<<<dim3(2048), 256, 0, stream>>>(Wh, a, f1, f2);
  transpose_bf16_kernel<<<dim3(64, 12, 4), 256, 0, stream>>>(Wh, WhT, 2048, 384);
  attn_kernel<<<dim3(512), 256, 0, stream>>>(f1, f2, adj, WhT, out);
}